// Round 1
// 979.535 us; speedup vs baseline: 1.1811x; 1.1811x over previous
//
#include <hip/hip_runtime.h>
#include <hip/hip_bf16.h>
#include <cstdint>
#include <cstddef>

// ---------------------------------------------------------------------------
// SwinLikeBlock, MI355X gfx950. Inputs f32, output f32.
// N=8, H=W=112, C=256, WS=7 -> 2048 windows x 49 tok, 8 heads x d=32,
// hidden=1024, T=100352.
//
// Round 7: MFMA attention. The previous scalar online-softmax loop (each lane
// serially over 49 keys, 32-FMA dep-chain dots + bf16 unpacks) was the 612 us
// bottleneck (VALUBusy 44%, MfmaUtil 4.6%, 1 wave/SIMD). Replaced with:
//   S = Q@K^T via mfma_16x16x32 (64x64, one K-step), row softmax via 16-lane
//   shfl reduce, P (normalized, bf16) -> per-wave LDS scratch (reused yb),
//   O = P@V via mfma (V stored TRANSPOSED in LDS at qkv epilogue so PV
//   B-frags are contiguous), O written into the dead Q region for proj.
// LDS: yb 32KB (LN tile / P scratch) + qkb 64x512 Q|K 64KB + vtb 256x64 V^T
// 32KB = 128KB, 1 block/CU (unchanged).
// LDS 16B-group XOR swizzle: group g of row r stored at (g&~7)|((g^r)&7).
// ---------------------------------------------------------------------------

typedef __bf16 bf16x8 __attribute__((ext_vector_type(8)));
typedef float f32x4 __attribute__((ext_vector_type(4)));

__device__ __forceinline__ float bf2f_lo(uint32_t u){ union{uint32_t u;float f;}c;c.u=u<<16;return c.f;}
__device__ __forceinline__ float bf2f_hi(uint32_t u){ union{uint32_t u;float f;}c;c.u=u&0xffff0000u;return c.f;}
__device__ __forceinline__ unsigned short f2bf(float f){
    union{float f;uint32_t u;}c;c.f=f;uint32_t u=c.u;u+=0x7fffu+((u>>16)&1u);return (unsigned short)(u>>16);}
__device__ __forceinline__ float gelu_f(float x){ return 0.5f*x*(1.0f+erff(x*0.70710678118654752f)); }
__device__ __forceinline__ int swz(int row,int g){ return (g & ~7) | ((g ^ row) & 7); }

// f32 -> bf16 convert, n4 = count/4
__global__ __launch_bounds__(256) void conv_k(
    const float* __restrict__ src, unsigned short* __restrict__ dst, int n4)
{
    int i = blockIdx.x * 256 + threadIdx.x;
    if (i >= n4) return;
    float4 v = *(const float4*)(src + (size_t)i * 4);
    uint2 o;
    o.x = (uint32_t)f2bf(v.x) | ((uint32_t)f2bf(v.y) << 16);
    o.y = (uint32_t)f2bf(v.z) | ((uint32_t)f2bf(v.w) << 16);
    *(uint2*)(dst + (size_t)i * 4) = o;
}

// ---------------------------------------------------------------------------
// Kernel A: fused LN1 + qkv + window attention (MFMA) + proj + residual.
// One block (256 thr, 4 waves) per window.
// ---------------------------------------------------------------------------
__global__ __launch_bounds__(256) void attn_half_k(
    const float* __restrict__ x, const float* __restrict__ g1, const float* __restrict__ b1,
    const unsigned short* __restrict__ Wqkv, const float* __restrict__ bqkv,
    const unsigned short* __restrict__ Wproj, const float* __restrict__ bproj,
    float* __restrict__ out)
{
    __shared__ __align__(16) unsigned short yb[64 * 256];   // LN tile, later P scratch
    __shared__ __align__(16) unsigned short qkb[64 * 512];  // rows=tok, ch 0..255=Q, 256..511=K
    __shared__ __align__(16) unsigned short vtb[256 * 64];  // rows=V channel, cols=tok
    const int t = threadIdx.x, lane = t & 63, w = t >> 6;
    const int quad = lane >> 4, l16 = lane & 15;
    const int widx = blockIdx.x;               // 0..2047
    const int img = widx >> 8, wi = widx & 255;
    const int wy = wi >> 4, wx = wi & 15;
    const size_t ibase = (size_t)img * 12544;

    // ---- LN1 into yb (swizzled); one wave per token ----
    for (int tok = w; tok < 49; tok += 4) {
        int r = tok / 7, c = tok - r * 7;
        size_t gtok = ibase + (size_t)(wy * 7 + r) * 112 + (wx * 7 + c);
        float4 v = *(const float4*)(x + gtok * 256 + lane * 4);
        float s = v.x + v.y + v.z + v.w;
        float q = v.x*v.x + v.y*v.y + v.z*v.z + v.w*v.w;
        #pragma unroll
        for (int o = 32; o > 0; o >>= 1) { s += __shfl_xor(s, o); q += __shfl_xor(q, o); }
        float mean = s * (1.f/256.f), var = q * (1.f/256.f) - mean * mean;
        float inv = rsqrtf(var + 1e-5f);
        float4 gv = *(const float4*)(g1 + lane * 4);
        float4 bv = *(const float4*)(b1 + lane * 4);
        uint2 pk;
        pk.x = (uint32_t)f2bf((v.x-mean)*inv*gv.x+bv.x) | ((uint32_t)f2bf((v.y-mean)*inv*gv.y+bv.y) << 16);
        pk.y = (uint32_t)f2bf((v.z-mean)*inv*gv.z+bv.z) | ((uint32_t)f2bf((v.w-mean)*inv*gv.w+bv.w) << 16);
        *(uint2*)&yb[tok*256 + swz(tok, lane >> 1)*8 + (lane & 1)*4] = pk;
    }
    {   // zero pad rows 49..63 (keeps qkv pad rows finite: bias only)
        uint2 z2; z2.x = 0u; z2.y = 0u;
        for (int i = t; i < 960; i += 256) {
            int row = 49 + (i >> 6), c4 = (i & 63) * 4;
            *(uint2*)&yb[row*256 + c4] = z2;
        }
    }
    __syncthreads();

    // ---- qkv GEMM: yb(64x256) @ Wqkv(768x256)^T + b -> qkb (Q|K) / vtb (V^T) ----
    for (int nc = 0; nc < 4; ++nc) {
        const int n0 = nc * 192 + w * 48;
        f32x4 acc[4][3] = {};
        #pragma unroll
        for (int ks = 0; ks < 8; ++ks) {
            bf16x8 af[4], bfr[3];
            #pragma unroll
            for (int mt = 0; mt < 4; ++mt) {
                int m = mt * 16 + l16;
                af[mt] = *(const bf16x8*)&yb[m*256 + swz(m, ks*4 + quad)*8];
            }
            #pragma unroll
            for (int nt = 0; nt < 3; ++nt) {
                int n = n0 + nt * 16 + l16;
                bfr[nt] = *(const bf16x8*)(Wqkv + (size_t)n*256 + ks*32 + quad*8);
            }
            #pragma unroll
            for (int mt = 0; mt < 4; ++mt)
                #pragma unroll
                for (int nt = 0; nt < 3; ++nt)
                    acc[mt][nt] = __builtin_amdgcn_mfma_f32_16x16x32_bf16(
                        af[mt], bfr[nt], acc[mt][nt], 0, 0, 0);
        }
        #pragma unroll
        for (int mt = 0; mt < 4; ++mt)
            #pragma unroll
            for (int nt = 0; nt < 3; ++nt) {
                int col = n0 + nt * 16 + l16;
                float bb = bqkv[col];
                #pragma unroll
                for (int r = 0; r < 4; ++r) {
                    int row = mt * 16 + quad * 4 + r;
                    unsigned short val = f2bf(acc[mt][nt][r] + bb);
                    if (col < 512)
                        qkb[row*512 + swz(row, col >> 3)*8 + (col & 7)] = val;
                    else
                        vtb[(col - 512)*64 + swz(col - 512, row >> 3)*8 + (row & 7)] = val;
                }
            }
    }
    __syncthreads();

    // ---- MFMA attention: wave w -> heads w and w+4 ----
    {
        const float scale = 0.17677669529663687f;   // 32^-0.5
        unsigned short* pbuf = &yb[w * 4096];       // 64x64 bf16 P scratch, per wave
        #pragma unroll
        for (int hh = 0; hh < 2; ++hh) {
            const int h = w + hh * 4;
            // S = Q @ K^T  (64x64, single K=32 step)
            bf16x8 aq[4], bk[4];
            #pragma unroll
            for (int mt = 0; mt < 4; ++mt) {
                int m = mt * 16 + l16;
                aq[mt] = *(const bf16x8*)&qkb[m*512 + swz(m, h*4 + quad)*8];
            }
            #pragma unroll
            for (int nt = 0; nt < 4; ++nt) {
                int n = nt * 16 + l16;
                bk[nt] = *(const bf16x8*)&qkb[n*512 + swz(n, 32 + h*4 + quad)*8];
            }
            f32x4 s[4][4] = {};
            #pragma unroll
            for (int mt = 0; mt < 4; ++mt)
                #pragma unroll
                for (int nt = 0; nt < 4; ++nt)
                    s[mt][nt] = __builtin_amdgcn_mfma_f32_16x16x32_bf16(
                        aq[mt], bk[nt], s[mt][nt], 0, 0, 0);

            // softmax per row; cols 49..63 masked; normalize folded into P
            #pragma unroll
            for (int mt = 0; mt < 4; ++mt)
                #pragma unroll
                for (int r = 0; r < 4; ++r) {
                    float v0 = s[mt][0][r];
                    float v1 = s[mt][1][r];
                    float v2 = s[mt][2][r];
                    float v3 = (l16 == 0) ? s[mt][3][r] : -1e30f;  // col 48+l16
                    float mxv = fmaxf(fmaxf(v0, v1), fmaxf(v2, v3));
                    #pragma unroll
                    for (int off = 8; off > 0; off >>= 1) mxv = fmaxf(mxv, __shfl_xor(mxv, off));
                    float p0 = __expf((v0 - mxv) * scale);
                    float p1 = __expf((v1 - mxv) * scale);
                    float p2 = __expf((v2 - mxv) * scale);
                    float p3 = __expf((v3 - mxv) * scale);
                    float ssum = p0 + p1 + p2 + p3;
                    #pragma unroll
                    for (int off = 8; off > 0; off >>= 1) ssum += __shfl_xor(ssum, off);
                    float inv = 1.f / ssum;
                    int row = mt * 16 + quad * 4 + r;
                    pbuf[row*64 + swz(row, 0 + (l16 >> 3))*8 + (l16 & 7)] = f2bf(p0 * inv);
                    pbuf[row*64 + swz(row, 2 + (l16 >> 3))*8 + (l16 & 7)] = f2bf(p1 * inv);
                    pbuf[row*64 + swz(row, 4 + (l16 >> 3))*8 + (l16 & 7)] = f2bf(p2 * inv);
                    pbuf[row*64 + swz(row, 6 + (l16 >> 3))*8 + (l16 & 7)] = f2bf(p3 * inv);
                }

            // O = P @ V  (64x32, K=64); V^T frags contiguous from vtb
            f32x4 o[4][2] = {};
            #pragma unroll
            for (int kst = 0; kst < 2; ++kst) {
                bf16x8 ap[4], bv[2];
                #pragma unroll
                for (int mt = 0; mt < 4; ++mt) {
                    int m = mt * 16 + l16;
                    ap[mt] = *(const bf16x8*)&pbuf[m*64 + swz(m, kst*4 + quad)*8];
                }
                #pragma unroll
                for (int nt = 0; nt < 2; ++nt) {
                    int c = h*32 + nt*16 + l16;
                    bv[nt] = *(const bf16x8*)&vtb[c*64 + swz(c, kst*4 + quad)*8];
                }
                #pragma unroll
                for (int mt = 0; mt < 4; ++mt)
                    #pragma unroll
                    for (int nt = 0; nt < 2; ++nt)
                        o[mt][nt] = __builtin_amdgcn_mfma_f32_16x16x32_bf16(
                            ap[mt], bv[nt], o[mt][nt], 0, 0, 0);
            }
            // write O into dead Q region (zero pad rows so proj pad stays 0)
            #pragma unroll
            for (int mt = 0; mt < 4; ++mt)
                #pragma unroll
                for (int nt = 0; nt < 2; ++nt)
                    #pragma unroll
                    for (int r = 0; r < 4; ++r) {
                        int row = mt * 16 + quad * 4 + r;
                        int ch = h*32 + nt*16 + l16;
                        float val = (row < 49) ? o[mt][nt][r] : 0.f;
                        qkb[row*512 + swz(row, ch >> 3)*8 + (ch & 7)] = f2bf(val);
                    }
        }
    }
    __syncthreads();

    // ---- proj: attnout(Q region of qkb) @ Wproj^T + b_proj + x -> out (f32) ----
    {
        const int n0 = w * 64;
        f32x4 acc[4][4] = {};
        #pragma unroll
        for (int ks = 0; ks < 8; ++ks) {
            bf16x8 af[4], bfr[4];
            #pragma unroll
            for (int mt = 0; mt < 4; ++mt) {
                int m = mt * 16 + l16;
                af[mt] = *(const bf16x8*)&qkb[m*512 + swz(m, ks*4 + quad)*8];
            }
            #pragma unroll
            for (int nt = 0; nt < 4; ++nt) {
                int n = n0 + nt * 16 + l16;
                bfr[nt] = *(const bf16x8*)(Wproj + (size_t)n*256 + ks*32 + quad*8);
            }
            #pragma unroll
            for (int mt = 0; mt < 4; ++mt)
                #pragma unroll
                for (int nt = 0; nt < 4; ++nt)
                    acc[mt][nt] = __builtin_amdgcn_mfma_f32_16x16x32_bf16(
                        af[mt], bfr[nt], acc[mt][nt], 0, 0, 0);
        }
        #pragma unroll
        for (int mt = 0; mt < 4; ++mt)
            #pragma unroll
            for (int r = 0; r < 4; ++r) {
                int row = mt * 16 + quad * 4 + r;
                if (row < 49) {
                    int rr = row / 7, cc = row - rr * 7;
                    size_t gtok = ibase + (size_t)(wy * 7 + rr) * 112 + (wx * 7 + cc);
                    #pragma unroll
                    for (int nt = 0; nt < 4; ++nt) {
                        int col = n0 + nt * 16 + l16;
                        out[gtok * 256 + col] = acc[mt][nt][r] + bproj[col] + x[gtok * 256 + col];
                    }
                }
            }
    }
}

// ---------------------------------------------------------------------------
// Kernel B: fused LN2 + fc1 + GELU + fc2 + residual, in-place f32 RMW on out.
// One block (256 thr, 4 waves) per 64 tokens. LDS: zb + hb = 64 KB.
// ---------------------------------------------------------------------------
__global__ __launch_bounds__(256) void mlp_half_k(
    const float* __restrict__ g2, const float* __restrict__ b2,
    const unsigned short* __restrict__ W1, const float* __restrict__ bf1,
    const unsigned short* __restrict__ W2, const float* __restrict__ bf2,
    float* __restrict__ out)
{
    __shared__ __align__(16) unsigned short zb[64 * 256];
    __shared__ __align__(16) unsigned short hb[64 * 256];
    const int t = threadIdx.x, lane = t & 63, w = t >> 6;
    const int quad = lane >> 4, l16 = lane & 15;
    const size_t m0 = (size_t)blockIdx.x * 64;

    // ---- LN2 from f32 out into zb ----
    for (int tok = w; tok < 64; tok += 4) {
        size_t row = m0 + tok;
        float4 v = *(const float4*)&out[row*256 + lane*4];
        float s = v.x+v.y+v.z+v.w, q = v.x*v.x+v.y*v.y+v.z*v.z+v.w*v.w;
        #pragma unroll
        for (int o = 32; o > 0; o >>= 1) { s += __shfl_xor(s, o); q += __shfl_xor(q, o); }
        float mean = s*(1.f/256.f), var = q*(1.f/256.f) - mean*mean;
        float inv = rsqrtf(var + 1e-5f);
        float4 gv = *(const float4*)(g2 + lane*4);
        float4 bv = *(const float4*)(b2 + lane*4);
        uint2 pk;
        pk.x = (uint32_t)f2bf((v.x-mean)*inv*gv.x+bv.x) | ((uint32_t)f2bf((v.y-mean)*inv*gv.y+bv.y) << 16);
        pk.y = (uint32_t)f2bf((v.z-mean)*inv*gv.z+bv.z) | ((uint32_t)f2bf((v.w-mean)*inv*gv.w+bv.w) << 16);
        *(uint2*)&zb[tok*256 + swz(tok, lane >> 1)*8 + (lane & 1)*4] = pk;
    }
    __syncthreads();

    f32x4 acc2[4][4] = {};
    for (int c = 0; c < 4; ++c) {                 // hidden chunks of 256
        const int hc0 = c * 256;
        f32x4 acc1[4][4] = {};
        #pragma unroll
        for (int ks = 0; ks < 8; ++ks) {          // fc1: K = 256
            bf16x8 af[4], bfr[4];
            #pragma unroll
            for (int mt = 0; mt < 4; ++mt) {
                int m = mt * 16 + l16;
                af[mt] = *(const bf16x8*)&zb[m*256 + swz(m, ks*4 + quad)*8];
            }
            #pragma unroll
            for (int nt = 0; nt < 4; ++nt) {
                int n = hc0 + w * 64 + nt * 16 + l16;
                bfr[nt] = *(const bf16x8*)(W1 + (size_t)n*256 + ks*32 + quad*8);
            }
            #pragma unroll
            for (int mt = 0; mt < 4; ++mt)
                #pragma unroll
                for (int nt = 0; nt < 4; ++nt)
                    acc1[mt][nt] = __builtin_amdgcn_mfma_f32_16x16x32_bf16(
                        af[mt], bfr[nt], acc1[mt][nt], 0, 0, 0);
        }
        __syncthreads();                          // prev chunk's hb reads done
        #pragma unroll
        for (int mt = 0; mt < 4; ++mt)
            #pragma unroll
            for (int nt = 0; nt < 4; ++nt) {
                int lc = w * 64 + nt * 16 + l16;
                float bb = bf1[hc0 + lc];
                #pragma unroll
                for (int r = 0; r < 4; ++r) {
                    int row = mt * 16 + quad * 4 + r;
                    hb[row*256 + swz(row, lc >> 3)*8 + (lc & 7)] =
                        f2bf(gelu_f(acc1[mt][nt][r] + bb));
                }
            }
        __syncthreads();
        #pragma unroll
        for (int ks = 0; ks < 8; ++ks) {          // fc2 partial-K
            bf16x8 af[4], bfr[4];
            #pragma unroll
            for (int mt = 0; mt < 4; ++mt) {
                int m = mt * 16 + l16;
                af[mt] = *(const bf16x8*)&hb[m*256 + swz(m, ks*4 + quad)*8];
            }
            #pragma unroll
            for (int nt = 0; nt < 4; ++nt) {
                int n = w * 64 + nt * 16 + l16;
                bfr[nt] = *(const bf16x8*)(W2 + (size_t)n*1024 + hc0 + ks*32 + quad*8);
            }
            #pragma unroll
            for (int mt = 0; mt < 4; ++mt)
                #pragma unroll
                for (int nt = 0; nt < 4; ++nt)
                    acc2[mt][nt] = __builtin_amdgcn_mfma_f32_16x16x32_bf16(
                        af[mt], bfr[nt], acc2[mt][nt], 0, 0, 0);
        }
    }
    // ---- epilogue: + b_fc2 + residual, f32 in-place ----
    #pragma unroll
    for (int mt = 0; mt < 4; ++mt)
        #pragma unroll
        for (int nt = 0; nt < 4; ++nt) {
            int col = w * 64 + nt * 16 + l16;
            float bb = bf2[col];
            #pragma unroll
            for (int r = 0; r < 4; ++r) {
                size_t row = m0 + mt * 16 + quad * 4 + r;
                out[row*256 + col] = acc2[mt][nt][r] + bb + out[row*256 + col];
            }
        }
}

// ---------------------------------------------------------------------------
extern "C" void kernel_launch(void* const* d_in, const int* in_sizes, int n_in,
                              void* d_out, int out_size, void* d_ws, size_t ws_size,
                              hipStream_t stream)
{
    const float* x      = (const float*)d_in[0];
    // d_in[1]=H, d_in[2]=W : compile-time constants (112).
    const float* g1     = (const float*)d_in[3];
    const float* b1     = (const float*)d_in[4];
    const float* w_qkv  = (const float*)d_in[5];
    const float* b_qkv  = (const float*)d_in[6];
    const float* w_proj = (const float*)d_in[7];
    const float* b_proj = (const float*)d_in[8];
    const float* g2     = (const float*)d_in[9];
    const float* b2     = (const float*)d_in[10];
    const float* w_fc1  = (const float*)d_in[11];
    const float* b_fc1  = (const float*)d_in[12];
    const float* w_fc2  = (const float*)d_in[13];
    const float* b_fc2  = (const float*)d_in[14];
    float* out = (float*)d_out;                      // f32 output

    // ws: converted bf16 weights only — 786432 elems = 1.5 MiB
    unsigned short* cWqkv  = (unsigned short*)d_ws;  // 196608
    unsigned short* cWproj = cWqkv  + 196608;        // 65536
    unsigned short* cWfc1  = cWproj + 65536;         // 262144
    unsigned short* cWfc2  = cWfc1  + 262144;        // 262144

    conv_k<<<192, 256, 0, stream>>>(w_qkv,  cWqkv,  49152);
    conv_k<<<64,  256, 0, stream>>>(w_proj, cWproj, 16384);
    conv_k<<<256, 256, 0, stream>>>(w_fc1,  cWfc1,  65536);
    conv_k<<<256, 256, 0, stream>>>(w_fc2,  cWfc2,  65536);

    attn_half_k<<<2048, 256, 0, stream>>>(x, g1, b1, cWqkv, b_qkv, cWproj, b_proj, out);
    mlp_half_k<<<1568, 256, 0, stream>>>(g2, b2, cWfc1, b_fc1, cWfc2, b_fc2, out);
}

// Round 2
// 759.316 us; speedup vs baseline: 1.5237x; 1.2900x over previous
//
#include <hip/hip_runtime.h>
#include <hip/hip_bf16.h>
#include <cstdint>
#include <cstddef>

// ---------------------------------------------------------------------------
// SwinLikeBlock, MI355X gfx950. Inputs f32, output f32.
// N=8, H=W=112, C=256, WS=7 -> 2048 windows x 49 tok, 8 heads x d=32,
// hidden=1024, T=100352.
//
// Round 8: occupancy. Round-7 counters: mlp MfmaUtil 9.6 / VALUBusy 17.6 /
// Occupancy 10.4% -> latency-bound at 1 wave/SIMD. Both kernels now run
// 512 threads (8 waves), each wave owning half the old N-tile:
//   attn: 1 head/wave, qkv 2x48 cols/wave, proj 32 cols/wave. P transposed
//         through per-wave 64x32 LDS chunks (2 rounds, fits 8x4KB in yb).
//         LDS 128KB, 1 block/CU, 2 waves/SIMD (was 1).
//   mlp:  fc1/fc2 32 cols/wave, __launch_bounds__(512,4) targets VGPR<=128
//         so 2 blocks/CU x 8 waves = 4 waves/SIMD (was 1).
// LDS 16B-group XOR swizzle: group g of row r stored at (g&~7)|((g^r)&7).
// ---------------------------------------------------------------------------

typedef __bf16 bf16x8 __attribute__((ext_vector_type(8)));
typedef float f32x4 __attribute__((ext_vector_type(4)));

__device__ __forceinline__ unsigned short f2bf(float f){
    union{float f;uint32_t u;}c;c.f=f;uint32_t u=c.u;u+=0x7fffu+((u>>16)&1u);return (unsigned short)(u>>16);}
__device__ __forceinline__ float gelu_f(float x){ return 0.5f*x*(1.0f+erff(x*0.70710678118654752f)); }
__device__ __forceinline__ int swz(int row,int g){ return (g & ~7) | ((g ^ row) & 7); }

// f32 -> bf16 convert, n4 = count/4
__global__ __launch_bounds__(256) void conv_k(
    const float* __restrict__ src, unsigned short* __restrict__ dst, int n4)
{
    int i = blockIdx.x * 256 + threadIdx.x;
    if (i >= n4) return;
    float4 v = *(const float4*)(src + (size_t)i * 4);
    uint2 o;
    o.x = (uint32_t)f2bf(v.x) | ((uint32_t)f2bf(v.y) << 16);
    o.y = (uint32_t)f2bf(v.z) | ((uint32_t)f2bf(v.w) << 16);
    *(uint2*)(dst + (size_t)i * 4) = o;
}

// ---------------------------------------------------------------------------
// Kernel A: fused LN1 + qkv + window attention (MFMA) + proj + residual.
// One block (512 thr, 8 waves) per window; wave w owns head w.
// ---------------------------------------------------------------------------
__global__ __launch_bounds__(512, 2) void attn_half_k(
    const float* __restrict__ x, const float* __restrict__ g1, const float* __restrict__ b1,
    const unsigned short* __restrict__ Wqkv, const float* __restrict__ bqkv,
    const unsigned short* __restrict__ Wproj, const float* __restrict__ bproj,
    float* __restrict__ out)
{
    __shared__ __align__(16) unsigned short yb[64 * 256];   // LN tile; later 8x(64x32) P scratch
    __shared__ __align__(16) unsigned short qkb[64 * 512];  // rows=tok, ch 0..255=Q(->attn out), 256..511=K
    __shared__ __align__(16) unsigned short vtb[256 * 64];  // rows=V channel, cols=tok
    const int t = threadIdx.x, lane = t & 63, w = t >> 6;   // w = 0..7
    const int quad = lane >> 4, l16 = lane & 15;
    const int widx = blockIdx.x;               // 0..2047
    const int img = widx >> 8, wi = widx & 255;
    const int wy = wi >> 4, wx = wi & 15;
    const size_t ibase = (size_t)img * 12544;

    // ---- LN1 into yb (swizzled); one wave per token ----
    for (int tok = w; tok < 49; tok += 8) {
        int r = tok / 7, c = tok - r * 7;
        size_t gtok = ibase + (size_t)(wy * 7 + r) * 112 + (wx * 7 + c);
        float4 v = *(const float4*)(x + gtok * 256 + lane * 4);
        float s = v.x + v.y + v.z + v.w;
        float q = v.x*v.x + v.y*v.y + v.z*v.z + v.w*v.w;
        #pragma unroll
        for (int o = 32; o > 0; o >>= 1) { s += __shfl_xor(s, o); q += __shfl_xor(q, o); }
        float mean = s * (1.f/256.f), var = q * (1.f/256.f) - mean * mean;
        float inv = rsqrtf(var + 1e-5f);
        float4 gv = *(const float4*)(g1 + lane * 4);
        float4 bv = *(const float4*)(b1 + lane * 4);
        uint2 pk;
        pk.x = (uint32_t)f2bf((v.x-mean)*inv*gv.x+bv.x) | ((uint32_t)f2bf((v.y-mean)*inv*gv.y+bv.y) << 16);
        pk.y = (uint32_t)f2bf((v.z-mean)*inv*gv.z+bv.z) | ((uint32_t)f2bf((v.w-mean)*inv*gv.w+bv.w) << 16);
        *(uint2*)&yb[tok*256 + swz(tok, lane >> 1)*8 + (lane & 1)*4] = pk;
    }
    {   // zero pad rows 49..63 (keeps qkv pad rows finite: bias only)
        uint2 z2; z2.x = 0u; z2.y = 0u;
        for (int i = t; i < 960; i += 512) {
            int row = 49 + (i >> 6), c4 = (i & 63) * 4;
            *(uint2*)&yb[row*256 + c4] = z2;
        }
    }
    __syncthreads();

    // ---- qkv GEMM: yb(64x256) @ Wqkv(768x256)^T + b -> qkb (Q|K) / vtb (V^T) ----
    for (int nc = 0; nc < 2; ++nc) {
        const int n0 = nc * 384 + w * 48;
        f32x4 acc[4][3] = {};
        #pragma unroll
        for (int ks = 0; ks < 8; ++ks) {
            bf16x8 af[4], bfr[3];
            #pragma unroll
            for (int mt = 0; mt < 4; ++mt) {
                int m = mt * 16 + l16;
                af[mt] = *(const bf16x8*)&yb[m*256 + swz(m, ks*4 + quad)*8];
            }
            #pragma unroll
            for (int nt = 0; nt < 3; ++nt) {
                int n = n0 + nt * 16 + l16;
                bfr[nt] = *(const bf16x8*)(Wqkv + (size_t)n*256 + ks*32 + quad*8);
            }
            #pragma unroll
            for (int mt = 0; mt < 4; ++mt)
                #pragma unroll
                for (int nt = 0; nt < 3; ++nt)
                    acc[mt][nt] = __builtin_amdgcn_mfma_f32_16x16x32_bf16(
                        af[mt], bfr[nt], acc[mt][nt], 0, 0, 0);
        }
        #pragma unroll
        for (int mt = 0; mt < 4; ++mt)
            #pragma unroll
            for (int nt = 0; nt < 3; ++nt) {
                int col = n0 + nt * 16 + l16;
                float bb = bqkv[col];
                #pragma unroll
                for (int r = 0; r < 4; ++r) {
                    int row = mt * 16 + quad * 4 + r;
                    unsigned short val = f2bf(acc[mt][nt][r] + bb);
                    if (col < 512)
                        qkb[row*512 + swz(row, col >> 3)*8 + (col & 7)] = val;
                    else
                        vtb[(col - 512)*64 + swz(col - 512, row >> 3)*8 + (row & 7)] = val;
                }
            }
    }
    __syncthreads();

    // ---- MFMA attention: wave w -> head w ----
    {
        const float scale = 0.17677669529663687f;   // 32^-0.5
        const int h = w;
        unsigned short* pbuf = &yb[w * 2048];       // 64x32 bf16 P chunk, per wave (4KB)

        // S = Q @ K^T  (64x64, single K=32 step)
        bf16x8 aq[4], bk[4];
        #pragma unroll
        for (int mt = 0; mt < 4; ++mt) {
            int m = mt * 16 + l16;
            aq[mt] = *(const bf16x8*)&qkb[m*512 + swz(m, h*4 + quad)*8];
        }
        #pragma unroll
        for (int nt = 0; nt < 4; ++nt) {
            int n = nt * 16 + l16;
            bk[nt] = *(const bf16x8*)&qkb[n*512 + swz(n, 32 + h*4 + quad)*8];
        }
        f32x4 s[4][4] = {};
        #pragma unroll
        for (int mt = 0; mt < 4; ++mt)
            #pragma unroll
            for (int nt = 0; nt < 4; ++nt)
                s[mt][nt] = __builtin_amdgcn_mfma_f32_16x16x32_bf16(
                    aq[mt], bk[nt], s[mt][nt], 0, 0, 0);

        // softmax per row; cols 49..63 masked; normalize folded into P.
        // Keep normalized P packed in registers (2 bf16 per u32).
        uint32_t pk01[4][4], pk23[4][4];
        #pragma unroll
        for (int mt = 0; mt < 4; ++mt)
            #pragma unroll
            for (int r = 0; r < 4; ++r) {
                float v0 = s[mt][0][r];
                float v1 = s[mt][1][r];
                float v2 = s[mt][2][r];
                float v3 = (l16 == 0) ? s[mt][3][r] : -1e30f;  // col 48+l16
                float mxv = fmaxf(fmaxf(v0, v1), fmaxf(v2, v3));
                #pragma unroll
                for (int off = 8; off > 0; off >>= 1) mxv = fmaxf(mxv, __shfl_xor(mxv, off));
                float p0 = __expf((v0 - mxv) * scale);
                float p1 = __expf((v1 - mxv) * scale);
                float p2 = __expf((v2 - mxv) * scale);
                float p3 = __expf((v3 - mxv) * scale);
                float ssum = p0 + p1 + p2 + p3;
                #pragma unroll
                for (int off = 8; off > 0; off >>= 1) ssum += __shfl_xor(ssum, off);
                float inv = 1.f / ssum;
                pk01[mt][r] = (uint32_t)f2bf(p0*inv) | ((uint32_t)f2bf(p1*inv) << 16);
                pk23[mt][r] = (uint32_t)f2bf(p2*inv) | ((uint32_t)f2bf(p3*inv) << 16);
            }

        // O = P @ V  (64x32, K=64), two K=32 rounds; P transposed via pbuf.
        // pbuf row = 32 shorts (4 groups of 8); 2-bit XOR swizzle on groups.
        f32x4 o[4][2] = {};
        #pragma unroll
        for (int kst = 0; kst < 2; ++kst) {
            #pragma unroll
            for (int mt = 0; mt < 4; ++mt)
                #pragma unroll
                for (int r = 0; r < 4; ++r) {
                    int row = mt * 16 + quad * 4 + r;
                    uint32_t pw = kst ? pk23[mt][r] : pk01[mt][r];
                    int c0 = l16;           // chunk col of p_{2kst}
                    int c1 = 16 + l16;      // chunk col of p_{2kst+1}
                    pbuf[row*32 + (((c0 >> 3) ^ row) & 3)*8 + (c0 & 7)] = (unsigned short)(pw & 0xffffu);
                    pbuf[row*32 + (((c1 >> 3) ^ row) & 3)*8 + (c1 & 7)] = (unsigned short)(pw >> 16);
                }
            bf16x8 ap[4], bv[2];
            #pragma unroll
            for (int mt = 0; mt < 4; ++mt) {
                int m = mt * 16 + l16;
                ap[mt] = *(const bf16x8*)&pbuf[m*32 + ((quad ^ m) & 3)*8];
            }
            #pragma unroll
            for (int nt = 0; nt < 2; ++nt) {
                int c = h*32 + nt*16 + l16;
                bv[nt] = *(const bf16x8*)&vtb[c*64 + swz(c, kst*4 + quad)*8];
            }
            #pragma unroll
            for (int mt = 0; mt < 4; ++mt)
                #pragma unroll
                for (int nt = 0; nt < 2; ++nt)
                    o[mt][nt] = __builtin_amdgcn_mfma_f32_16x16x32_bf16(
                        ap[mt], bv[nt], o[mt][nt], 0, 0, 0);
        }
        // write O into dead Q region (zero pad rows so proj pad stays 0)
        #pragma unroll
        for (int mt = 0; mt < 4; ++mt)
            #pragma unroll
            for (int nt = 0; nt < 2; ++nt)
                #pragma unroll
                for (int r = 0; r < 4; ++r) {
                    int row = mt * 16 + quad * 4 + r;
                    int ch = h*32 + nt*16 + l16;
                    float val = (row < 49) ? o[mt][nt][r] : 0.f;
                    qkb[row*512 + swz(row, ch >> 3)*8 + (ch & 7)] = f2bf(val);
                }
    }
    __syncthreads();

    // ---- proj: attnout(Q region of qkb) @ Wproj^T + b_proj + x -> out (f32) ----
    {
        const int n0 = w * 32;
        f32x4 acc[4][2] = {};
        #pragma unroll
        for (int ks = 0; ks < 8; ++ks) {
            bf16x8 af[4], bfr[2];
            #pragma unroll
            for (int mt = 0; mt < 4; ++mt) {
                int m = mt * 16 + l16;
                af[mt] = *(const bf16x8*)&qkb[m*512 + swz(m, ks*4 + quad)*8];
            }
            #pragma unroll
            for (int nt = 0; nt < 2; ++nt) {
                int n = n0 + nt * 16 + l16;
                bfr[nt] = *(const bf16x8*)(Wproj + (size_t)n*256 + ks*32 + quad*8);
            }
            #pragma unroll
            for (int mt = 0; mt < 4; ++mt)
                #pragma unroll
                for (int nt = 0; nt < 2; ++nt)
                    acc[mt][nt] = __builtin_amdgcn_mfma_f32_16x16x32_bf16(
                        af[mt], bfr[nt], acc[mt][nt], 0, 0, 0);
        }
        #pragma unroll
        for (int mt = 0; mt < 4; ++mt)
            #pragma unroll
            for (int r = 0; r < 4; ++r) {
                int row = mt * 16 + quad * 4 + r;
                if (row < 49) {
                    int rr = row / 7, cc = row - rr * 7;
                    size_t gtok = ibase + (size_t)(wy * 7 + rr) * 112 + (wx * 7 + cc);
                    #pragma unroll
                    for (int nt = 0; nt < 2; ++nt) {
                        int col = n0 + nt * 16 + l16;
                        out[gtok * 256 + col] = acc[mt][nt][r] + bproj[col] + x[gtok * 256 + col];
                    }
                }
            }
    }
}

// ---------------------------------------------------------------------------
// Kernel B: fused LN2 + fc1 + GELU + fc2 + residual, in-place f32 RMW on out.
// One block (512 thr, 8 waves) per 64 tokens; wave w owns 32 output cols.
// LDS zb + hb = 64 KB -> 2 blocks/CU; VGPR target <=128 for 4 waves/SIMD.
// ---------------------------------------------------------------------------
__global__ __launch_bounds__(512, 4) void mlp_half_k(
    const float* __restrict__ g2, const float* __restrict__ b2,
    const unsigned short* __restrict__ W1, const float* __restrict__ bf1,
    const unsigned short* __restrict__ W2, const float* __restrict__ bf2,
    float* __restrict__ out)
{
    __shared__ __align__(16) unsigned short zb[64 * 256];
    __shared__ __align__(16) unsigned short hb[64 * 256];
    const int t = threadIdx.x, lane = t & 63, w = t >> 6;   // w = 0..7
    const int quad = lane >> 4, l16 = lane & 15;
    const size_t m0 = (size_t)blockIdx.x * 64;

    // ---- LN2 from f32 out into zb ----
    for (int tok = w; tok < 64; tok += 8) {
        size_t row = m0 + tok;
        float4 v = *(const float4*)&out[row*256 + lane*4];
        float s = v.x+v.y+v.z+v.w, q = v.x*v.x+v.y*v.y+v.z*v.z+v.w*v.w;
        #pragma unroll
        for (int o = 32; o > 0; o >>= 1) { s += __shfl_xor(s, o); q += __shfl_xor(q, o); }
        float mean = s*(1.f/256.f), var = q*(1.f/256.f) - mean*mean;
        float inv = rsqrtf(var + 1e-5f);
        float4 gv = *(const float4*)(g2 + lane*4);
        float4 bv = *(const float4*)(b2 + lane*4);
        uint2 pk;
        pk.x = (uint32_t)f2bf((v.x-mean)*inv*gv.x+bv.x) | ((uint32_t)f2bf((v.y-mean)*inv*gv.y+bv.y) << 16);
        pk.y = (uint32_t)f2bf((v.z-mean)*inv*gv.z+bv.z) | ((uint32_t)f2bf((v.w-mean)*inv*gv.w+bv.w) << 16);
        *(uint2*)&zb[tok*256 + swz(tok, lane >> 1)*8 + (lane & 1)*4] = pk;
    }
    __syncthreads();

    f32x4 acc2[4][2] = {};
    for (int c = 0; c < 4; ++c) {                 // hidden chunks of 256
        const int hc0 = c * 256;
        f32x4 acc1[4][2] = {};
        #pragma unroll
        for (int ks = 0; ks < 8; ++ks) {          // fc1: K = 256
            bf16x8 af[4], bfr[2];
            #pragma unroll
            for (int mt = 0; mt < 4; ++mt) {
                int m = mt * 16 + l16;
                af[mt] = *(const bf16x8*)&zb[m*256 + swz(m, ks*4 + quad)*8];
            }
            #pragma unroll
            for (int nt = 0; nt < 2; ++nt) {
                int n = hc0 + w * 32 + nt * 16 + l16;
                bfr[nt] = *(const bf16x8*)(W1 + (size_t)n*256 + ks*32 + quad*8);
            }
            #pragma unroll
            for (int mt = 0; mt < 4; ++mt)
                #pragma unroll
                for (int nt = 0; nt < 2; ++nt)
                    acc1[mt][nt] = __builtin_amdgcn_mfma_f32_16x16x32_bf16(
                        af[mt], bfr[nt], acc1[mt][nt], 0, 0, 0);
        }
        __syncthreads();                          // prev chunk's hb reads done
        #pragma unroll
        for (int mt = 0; mt < 4; ++mt)
            #pragma unroll
            for (int nt = 0; nt < 2; ++nt) {
                int lc = w * 32 + nt * 16 + l16;
                float bb = bf1[hc0 + lc];
                #pragma unroll
                for (int r = 0; r < 4; ++r) {
                    int row = mt * 16 + quad * 4 + r;
                    hb[row*256 + swz(row, lc >> 3)*8 + (lc & 7)] =
                        f2bf(gelu_f(acc1[mt][nt][r] + bb));
                }
            }
        __syncthreads();
        #pragma unroll
        for (int ks = 0; ks < 8; ++ks) {          // fc2 partial-K
            bf16x8 af[4], bfr[2];
            #pragma unroll
            for (int mt = 0; mt < 4; ++mt) {
                int m = mt * 16 + l16;
                af[mt] = *(const bf16x8*)&hb[m*256 + swz(m, ks*4 + quad)*8];
            }
            #pragma unroll
            for (int nt = 0; nt < 2; ++nt) {
                int n = w * 32 + nt * 16 + l16;
                bfr[nt] = *(const bf16x8*)(W2 + (size_t)n*1024 + hc0 + ks*32 + quad*8);
            }
            #pragma unroll
            for (int mt = 0; mt < 4; ++mt)
                #pragma unroll
                for (int nt = 0; nt < 2; ++nt)
                    acc2[mt][nt] = __builtin_amdgcn_mfma_f32_16x16x32_bf16(
                        af[mt], bfr[nt], acc2[mt][nt], 0, 0, 0);
        }
    }
    // ---- epilogue: + b_fc2 + residual, f32 in-place ----
    #pragma unroll
    for (int mt = 0; mt < 4; ++mt)
        #pragma unroll
        for (int nt = 0; nt < 2; ++nt) {
            int col = w * 32 + nt * 16 + l16;
            float bb = bf2[col];
            #pragma unroll
            for (int r = 0; r < 4; ++r) {
                size_t row = m0 + mt * 16 + quad * 4 + r;
                out[row*256 + col] = acc2[mt][nt][r] + bb + out[row*256 + col];
            }
        }
}

// ---------------------------------------------------------------------------
extern "C" void kernel_launch(void* const* d_in, const int* in_sizes, int n_in,
                              void* d_out, int out_size, void* d_ws, size_t ws_size,
                              hipStream_t stream)
{
    const float* x      = (const float*)d_in[0];
    // d_in[1]=H, d_in[2]=W : compile-time constants (112).
    const float* g1     = (const float*)d_in[3];
    const float* b1     = (const float*)d_in[4];
    const float* w_qkv  = (const float*)d_in[5];
    const float* b_qkv  = (const float*)d_in[6];
    const float* w_proj = (const float*)d_in[7];
    const float* b_proj = (const float*)d_in[8];
    const float* g2     = (const float*)d_in[9];
    const float* b2     = (const float*)d_in[10];
    const float* w_fc1  = (const float*)d_in[11];
    const float* b_fc1  = (const float*)d_in[12];
    const float* w_fc2  = (const float*)d_in[13];
    const float* b_fc2  = (const float*)d_in[14];
    float* out = (float*)d_out;                      // f32 output

    // ws: converted bf16 weights only — 786432 elems = 1.5 MiB
    unsigned short* cWqkv  = (unsigned short*)d_ws;  // 196608
    unsigned short* cWproj = cWqkv  + 196608;        // 65536
    unsigned short* cWfc1  = cWproj + 65536;         // 262144
    unsigned short* cWfc2  = cWfc1  + 262144;        // 262144

    conv_k<<<192, 256, 0, stream>>>(w_qkv,  cWqkv,  49152);
    conv_k<<<64,  256, 0, stream>>>(w_proj, cWproj, 16384);
    conv_k<<<256, 256, 0, stream>>>(w_fc1,  cWfc1,  65536);
    conv_k<<<256, 256, 0, stream>>>(w_fc2,  cWfc2,  65536);

    attn_half_k<<<2048, 512, 0, stream>>>(x, g1, b1, cWqkv, b_qkv, cWproj, b_proj, out);
    mlp_half_k<<<1568, 512, 0, stream>>>(g2, b2, cWfc1, b_fc1, cWfc2, b_fc2, out);
}

// Round 3
// 715.995 us; speedup vs baseline: 1.6159x; 1.0605x over previous
//
#include <hip/hip_runtime.h>
#include <hip/hip_bf16.h>
#include <cstdint>
#include <cstddef>

// ---------------------------------------------------------------------------
// SwinLikeBlock, MI355X gfx950. Inputs f32, output f32.
// N=8, H=W=112, C=256, WS=7 -> 2048 windows x 49 tok, 8 heads x d=32,
// hidden=1024, T=100352.
//
// Round 9: attn occupancy. Round-8 attn counters: MfmaUtil 4.1 / VALUBusy 10.9
// / Occupancy 8.9% / 8.4M bank conflicts -> ~80% stall at 2 waves/SIMD.
//   attn: 1024 thr (16 waves) = 4 waves/SIMD at 128KB LDS. 2 waves/head
//         (32 query rows each), qkv 48 cols/wave single pass, proj 16
//         cols/wave. P scratch relocated into the dead Q|K region of qkb
//         (frags in regs, barrier-protected) with 40-short (80B) row stride:
//         16B-aligned for b128, banks de-phase (2-way max, free).
//   mlp:  unchanged (512 thr, 2 blocks/CU, VGPR 64).
// LDS 16B-group XOR swizzle: group g of row r stored at (g&~7)|((g^r)&7).
// ---------------------------------------------------------------------------

typedef __bf16 bf16x8 __attribute__((ext_vector_type(8)));
typedef float f32x4 __attribute__((ext_vector_type(4)));

__device__ __forceinline__ unsigned short f2bf(float f){
    union{float f;uint32_t u;}c;c.f=f;uint32_t u=c.u;u+=0x7fffu+((u>>16)&1u);return (unsigned short)(u>>16);}
__device__ __forceinline__ float gelu_f(float x){ return 0.5f*x*(1.0f+erff(x*0.70710678118654752f)); }
__device__ __forceinline__ int swz(int row,int g){ return (g & ~7) | ((g ^ row) & 7); }

// f32 -> bf16 convert, n4 = count/4
__global__ __launch_bounds__(256) void conv_k(
    const float* __restrict__ src, unsigned short* __restrict__ dst, int n4)
{
    int i = blockIdx.x * 256 + threadIdx.x;
    if (i >= n4) return;
    float4 v = *(const float4*)(src + (size_t)i * 4);
    uint2 o;
    o.x = (uint32_t)f2bf(v.x) | ((uint32_t)f2bf(v.y) << 16);
    o.y = (uint32_t)f2bf(v.z) | ((uint32_t)f2bf(v.w) << 16);
    *(uint2*)(dst + (size_t)i * 4) = o;
}

// ---------------------------------------------------------------------------
// Kernel A: fused LN1 + qkv + window attention (MFMA) + proj + residual.
// One block (1024 thr, 16 waves) per window; waves (h, h+8) share head h.
// ---------------------------------------------------------------------------
__global__ __launch_bounds__(1024, 4) void attn_half_k(
    const float* __restrict__ x, const float* __restrict__ g1, const float* __restrict__ b1,
    const unsigned short* __restrict__ Wqkv, const float* __restrict__ bqkv,
    const unsigned short* __restrict__ Wproj, const float* __restrict__ bproj,
    float* __restrict__ out)
{
    __shared__ __align__(16) unsigned short yb[64 * 256];   // LN tile
    __shared__ __align__(16) unsigned short qkb[64 * 512];  // rows=tok, ch 0..255=Q(->P scratch->attn out), 256..511=K
    __shared__ __align__(16) unsigned short vtb[256 * 64];  // rows=V channel, cols=tok
    const int t = threadIdx.x, lane = t & 63, w = t >> 6;   // w = 0..15
    const int quad = lane >> 4, l16 = lane & 15;
    const int widx = blockIdx.x;               // 0..2047
    const int img = widx >> 8, wi = widx & 255;
    const int wy = wi >> 4, wx = wi & 15;
    const size_t ibase = (size_t)img * 12544;

    // ---- LN1 into yb (swizzled); one wave per token ----
    for (int tok = w; tok < 49; tok += 16) {
        int r = tok / 7, c = tok - r * 7;
        size_t gtok = ibase + (size_t)(wy * 7 + r) * 112 + (wx * 7 + c);
        float4 v = *(const float4*)(x + gtok * 256 + lane * 4);
        float s = v.x + v.y + v.z + v.w;
        float q = v.x*v.x + v.y*v.y + v.z*v.z + v.w*v.w;
        #pragma unroll
        for (int o = 32; o > 0; o >>= 1) { s += __shfl_xor(s, o); q += __shfl_xor(q, o); }
        float mean = s * (1.f/256.f), var = q * (1.f/256.f) - mean * mean;
        float inv = rsqrtf(var + 1e-5f);
        float4 gv = *(const float4*)(g1 + lane * 4);
        float4 bv = *(const float4*)(b1 + lane * 4);
        uint2 pk;
        pk.x = (uint32_t)f2bf((v.x-mean)*inv*gv.x+bv.x) | ((uint32_t)f2bf((v.y-mean)*inv*gv.y+bv.y) << 16);
        pk.y = (uint32_t)f2bf((v.z-mean)*inv*gv.z+bv.z) | ((uint32_t)f2bf((v.w-mean)*inv*gv.w+bv.w) << 16);
        *(uint2*)&yb[tok*256 + swz(tok, lane >> 1)*8 + (lane & 1)*4] = pk;
    }
    {   // zero pad rows 49..63 (keeps qkv pad rows finite: bias only)
        uint2 z2; z2.x = 0u; z2.y = 0u;
        for (int i = t; i < 960; i += 1024) {
            int row = 49 + (i >> 6), c4 = (i & 63) * 4;
            *(uint2*)&yb[row*256 + c4] = z2;
        }
    }
    __syncthreads();

    // ---- qkv GEMM: yb(64x256) @ Wqkv(768x256)^T + b -> qkb (Q|K) / vtb (V^T) ----
    {
        const int n0 = w * 48;
        f32x4 acc[4][3] = {};
        #pragma unroll
        for (int ks = 0; ks < 8; ++ks) {
            bf16x8 af[4], bfr[3];
            #pragma unroll
            for (int mt = 0; mt < 4; ++mt) {
                int m = mt * 16 + l16;
                af[mt] = *(const bf16x8*)&yb[m*256 + swz(m, ks*4 + quad)*8];
            }
            #pragma unroll
            for (int nt = 0; nt < 3; ++nt) {
                int n = n0 + nt * 16 + l16;
                bfr[nt] = *(const bf16x8*)(Wqkv + (size_t)n*256 + ks*32 + quad*8);
            }
            #pragma unroll
            for (int mt = 0; mt < 4; ++mt)
                #pragma unroll
                for (int nt = 0; nt < 3; ++nt)
                    acc[mt][nt] = __builtin_amdgcn_mfma_f32_16x16x32_bf16(
                        af[mt], bfr[nt], acc[mt][nt], 0, 0, 0);
        }
        #pragma unroll
        for (int mt = 0; mt < 4; ++mt)
            #pragma unroll
            for (int nt = 0; nt < 3; ++nt) {
                int col = n0 + nt * 16 + l16;
                float bb = bqkv[col];
                #pragma unroll
                for (int r = 0; r < 4; ++r) {
                    int row = mt * 16 + quad * 4 + r;
                    unsigned short val = f2bf(acc[mt][nt][r] + bb);
                    if (col < 512)
                        qkb[row*512 + swz(row, col >> 3)*8 + (col & 7)] = val;
                    else
                        vtb[(col - 512)*64 + swz(col - 512, row >> 3)*8 + (row & 7)] = val;
                }
            }
    }
    __syncthreads();

    // ---- MFMA attention: waves (h, h+8) -> head h, 32 query rows each ----
    {
        const float scale = 0.17677669529663687f;   // 32^-0.5
        const int h = w & 7, half = w >> 3;
        unsigned short* pbuf = qkb + w * 1280;      // 32 rows x 40 shorts, per wave (2.5KB)

        // Load all S fragments from qkb into registers, then free qkb for P.
        bf16x8 aq[2], bk[4];
        #pragma unroll
        for (int mtl = 0; mtl < 2; ++mtl) {
            int m = half*32 + mtl*16 + l16;
            aq[mtl] = *(const bf16x8*)&qkb[m*512 + swz(m, h*4 + quad)*8];
        }
        #pragma unroll
        for (int nt = 0; nt < 4; ++nt) {
            int n = nt * 16 + l16;
            bk[nt] = *(const bf16x8*)&qkb[n*512 + swz(n, 32 + h*4 + quad)*8];
        }
        __syncthreads();   // all frag loads done before any wave writes P into qkb

        // S = Q @ K^T  (32x64 per wave, single K=32 step)
        f32x4 s[2][4] = {};
        #pragma unroll
        for (int mtl = 0; mtl < 2; ++mtl)
            #pragma unroll
            for (int nt = 0; nt < 4; ++nt)
                s[mtl][nt] = __builtin_amdgcn_mfma_f32_16x16x32_bf16(
                    aq[mtl], bk[nt], s[mtl][nt], 0, 0, 0);

        // softmax per row; cols 49..63 masked; normalize folded into P.
        uint32_t pk01[2][4], pk23[2][4];
        #pragma unroll
        for (int mtl = 0; mtl < 2; ++mtl)
            #pragma unroll
            for (int r = 0; r < 4; ++r) {
                float v0 = s[mtl][0][r];
                float v1 = s[mtl][1][r];
                float v2 = s[mtl][2][r];
                float v3 = (l16 == 0) ? s[mtl][3][r] : -1e30f;  // col 48+l16
                float mxv = fmaxf(fmaxf(v0, v1), fmaxf(v2, v3));
                #pragma unroll
                for (int off = 8; off > 0; off >>= 1) mxv = fmaxf(mxv, __shfl_xor(mxv, off));
                float p0 = __expf((v0 - mxv) * scale);
                float p1 = __expf((v1 - mxv) * scale);
                float p2 = __expf((v2 - mxv) * scale);
                float p3 = __expf((v3 - mxv) * scale);
                float ssum = p0 + p1 + p2 + p3;
                #pragma unroll
                for (int off = 8; off > 0; off >>= 1) ssum += __shfl_xor(ssum, off);
                float inv = 1.f / ssum;
                pk01[mtl][r] = (uint32_t)f2bf(p0*inv) | ((uint32_t)f2bf(p1*inv) << 16);
                pk23[mtl][r] = (uint32_t)f2bf(p2*inv) | ((uint32_t)f2bf(p3*inv) << 16);
            }

        // O = P @ V  (32x32 per wave, K=64), two K=32 rounds; P via pbuf
        // (row stride 40 shorts = 80B: 16B-aligned, 2-way bank alias max).
        f32x4 o[2][2] = {};
        #pragma unroll
        for (int kst = 0; kst < 2; ++kst) {
            #pragma unroll
            for (int mtl = 0; mtl < 2; ++mtl)
                #pragma unroll
                for (int r = 0; r < 4; ++r) {
                    int lr = mtl*16 + quad*4 + r;
                    uint32_t pw = kst ? pk23[mtl][r] : pk01[mtl][r];
                    pbuf[lr*40 + l16]      = (unsigned short)(pw & 0xffffu);
                    pbuf[lr*40 + 16 + l16] = (unsigned short)(pw >> 16);
                }
            bf16x8 ap[2], bv[2];
            #pragma unroll
            for (int mtl = 0; mtl < 2; ++mtl) {
                int m = mtl * 16 + l16;
                ap[mtl] = *(const bf16x8*)&pbuf[m*40 + quad*8];
            }
            #pragma unroll
            for (int nt = 0; nt < 2; ++nt) {
                int c = h*32 + nt*16 + l16;
                bv[nt] = *(const bf16x8*)&vtb[c*64 + swz(c, kst*4 + quad)*8];
            }
            #pragma unroll
            for (int mtl = 0; mtl < 2; ++mtl)
                #pragma unroll
                for (int nt = 0; nt < 2; ++nt)
                    o[mtl][nt] = __builtin_amdgcn_mfma_f32_16x16x32_bf16(
                        ap[mtl], bv[nt], o[mtl][nt], 0, 0, 0);
        }
        __syncthreads();   // all P reads done before O overwrites qkb

        // write O into Q region (zero pad rows so proj pad stays 0)
        #pragma unroll
        for (int mtl = 0; mtl < 2; ++mtl)
            #pragma unroll
            for (int nt = 0; nt < 2; ++nt)
                #pragma unroll
                for (int r = 0; r < 4; ++r) {
                    int row = half*32 + mtl*16 + quad*4 + r;
                    int ch = h*32 + nt*16 + l16;
                    float val = (row < 49) ? o[mtl][nt][r] : 0.f;
                    qkb[row*512 + swz(row, ch >> 3)*8 + (ch & 7)] = f2bf(val);
                }
    }
    __syncthreads();

    // ---- proj: attnout(Q region of qkb) @ Wproj^T + b_proj + x -> out (f32) ----
    {
        const int n0 = w * 16;
        f32x4 acc[4];
        #pragma unroll
        for (int mt = 0; mt < 4; ++mt) acc[mt] = (f32x4){0.f,0.f,0.f,0.f};
        #pragma unroll
        for (int ks = 0; ks < 8; ++ks) {
            bf16x8 af[4], bfr;
            #pragma unroll
            for (int mt = 0; mt < 4; ++mt) {
                int m = mt * 16 + l16;
                af[mt] = *(const bf16x8*)&qkb[m*512 + swz(m, ks*4 + quad)*8];
            }
            {
                int n = n0 + l16;
                bfr = *(const bf16x8*)(Wproj + (size_t)n*256 + ks*32 + quad*8);
            }
            #pragma unroll
            for (int mt = 0; mt < 4; ++mt)
                acc[mt] = __builtin_amdgcn_mfma_f32_16x16x32_bf16(
                    af[mt], bfr, acc[mt], 0, 0, 0);
        }
        #pragma unroll
        for (int mt = 0; mt < 4; ++mt)
            #pragma unroll
            for (int r = 0; r < 4; ++r) {
                int row = mt * 16 + quad * 4 + r;
                if (row < 49) {
                    int rr = row / 7, cc = row - rr * 7;
                    size_t gtok = ibase + (size_t)(wy * 7 + rr) * 112 + (wx * 7 + cc);
                    int col = n0 + l16;
                    out[gtok * 256 + col] = acc[mt][r] + bproj[col] + x[gtok * 256 + col];
                }
            }
    }
}

// ---------------------------------------------------------------------------
// Kernel B: fused LN2 + fc1 + GELU + fc2 + residual, in-place f32 RMW on out.
// One block (512 thr, 8 waves) per 64 tokens; wave w owns 32 output cols.
// LDS zb + hb = 64 KB -> 2 blocks/CU; VGPR 64 -> 4 waves/SIMD.
// ---------------------------------------------------------------------------
__global__ __launch_bounds__(512, 4) void mlp_half_k(
    const float* __restrict__ g2, const float* __restrict__ b2,
    const unsigned short* __restrict__ W1, const float* __restrict__ bf1,
    const unsigned short* __restrict__ W2, const float* __restrict__ bf2,
    float* __restrict__ out)
{
    __shared__ __align__(16) unsigned short zb[64 * 256];
    __shared__ __align__(16) unsigned short hb[64 * 256];
    const int t = threadIdx.x, lane = t & 63, w = t >> 6;   // w = 0..7
    const int quad = lane >> 4, l16 = lane & 15;
    const size_t m0 = (size_t)blockIdx.x * 64;

    // ---- LN2 from f32 out into zb ----
    for (int tok = w; tok < 64; tok += 8) {
        size_t row = m0 + tok;
        float4 v = *(const float4*)&out[row*256 + lane*4];
        float s = v.x+v.y+v.z+v.w, q = v.x*v.x+v.y*v.y+v.z*v.z+v.w*v.w;
        #pragma unroll
        for (int o = 32; o > 0; o >>= 1) { s += __shfl_xor(s, o); q += __shfl_xor(q, o); }
        float mean = s*(1.f/256.f), var = q*(1.f/256.f) - mean*mean;
        float inv = rsqrtf(var + 1e-5f);
        float4 gv = *(const float4*)(g2 + lane*4);
        float4 bv = *(const float4*)(b2 + lane*4);
        uint2 pk;
        pk.x = (uint32_t)f2bf((v.x-mean)*inv*gv.x+bv.x) | ((uint32_t)f2bf((v.y-mean)*inv*gv.y+bv.y) << 16);
        pk.y = (uint32_t)f2bf((v.z-mean)*inv*gv.z+bv.z) | ((uint32_t)f2bf((v.w-mean)*inv*gv.w+bv.w) << 16);
        *(uint2*)&zb[tok*256 + swz(tok, lane >> 1)*8 + (lane & 1)*4] = pk;
    }
    __syncthreads();

    f32x4 acc2[4][2] = {};
    for (int c = 0; c < 4; ++c) {                 // hidden chunks of 256
        const int hc0 = c * 256;
        f32x4 acc1[4][2] = {};
        #pragma unroll
        for (int ks = 0; ks < 8; ++ks) {          // fc1: K = 256
            bf16x8 af[4], bfr[2];
            #pragma unroll
            for (int mt = 0; mt < 4; ++mt) {
                int m = mt * 16 + l16;
                af[mt] = *(const bf16x8*)&zb[m*256 + swz(m, ks*4 + quad)*8];
            }
            #pragma unroll
            for (int nt = 0; nt < 2; ++nt) {
                int n = hc0 + w * 32 + nt * 16 + l16;
                bfr[nt] = *(const bf16x8*)(W1 + (size_t)n*256 + ks*32 + quad*8);
            }
            #pragma unroll
            for (int mt = 0; mt < 4; ++mt)
                #pragma unroll
                for (int nt = 0; nt < 2; ++nt)
                    acc1[mt][nt] = __builtin_amdgcn_mfma_f32_16x16x32_bf16(
                        af[mt], bfr[nt], acc1[mt][nt], 0, 0, 0);
        }
        __syncthreads();                          // prev chunk's hb reads done
        #pragma unroll
        for (int mt = 0; mt < 4; ++mt)
            #pragma unroll
            for (int nt = 0; nt < 2; ++nt) {
                int lc = w * 32 + nt * 16 + l16;
                float bb = bf1[hc0 + lc];
                #pragma unroll
                for (int r = 0; r < 4; ++r) {
                    int row = mt * 16 + quad * 4 + r;
                    hb[row*256 + swz(row, lc >> 3)*8 + (lc & 7)] =
                        f2bf(gelu_f(acc1[mt][nt][r] + bb));
                }
            }
        __syncthreads();
        #pragma unroll
        for (int ks = 0; ks < 8; ++ks) {          // fc2 partial-K
            bf16x8 af[4], bfr[2];
            #pragma unroll
            for (int mt = 0; mt < 4; ++mt) {
                int m = mt * 16 + l16;
                af[mt] = *(const bf16x8*)&hb[m*256 + swz(m, ks*4 + quad)*8];
            }
            #pragma unroll
            for (int nt = 0; nt < 2; ++nt) {
                int n = w * 32 + nt * 16 + l16;
                bfr[nt] = *(const bf16x8*)(W2 + (size_t)n*1024 + hc0 + ks*32 + quad*8);
            }
            #pragma unroll
            for (int mt = 0; mt < 4; ++mt)
                #pragma unroll
                for (int nt = 0; nt < 2; ++nt)
                    acc2[mt][nt] = __builtin_amdgcn_mfma_f32_16x16x32_bf16(
                        af[mt], bfr[nt], acc2[mt][nt], 0, 0, 0);
        }
    }
    // ---- epilogue: + b_fc2 + residual, f32 in-place ----
    #pragma unroll
    for (int mt = 0; mt < 4; ++mt)
        #pragma unroll
        for (int nt = 0; nt < 2; ++nt) {
            int col = w * 32 + nt * 16 + l16;
            float bb = bf2[col];
            #pragma unroll
            for (int r = 0; r < 4; ++r) {
                size_t row = m0 + mt * 16 + quad * 4 + r;
                out[row*256 + col] = acc2[mt][nt][r] + bb + out[row*256 + col];
            }
        }
}

// ---------------------------------------------------------------------------
extern "C" void kernel_launch(void* const* d_in, const int* in_sizes, int n_in,
                              void* d_out, int out_size, void* d_ws, size_t ws_size,
                              hipStream_t stream)
{
    const float* x      = (const float*)d_in[0];
    // d_in[1]=H, d_in[2]=W : compile-time constants (112).
    const float* g1     = (const float*)d_in[3];
    const float* b1     = (const float*)d_in[4];
    const float* w_qkv  = (const float*)d_in[5];
    const float* b_qkv  = (const float*)d_in[6];
    const float* w_proj = (const float*)d_in[7];
    const float* b_proj = (const float*)d_in[8];
    const float* g2     = (const float*)d_in[9];
    const float* b2     = (const float*)d_in[10];
    const float* w_fc1  = (const float*)d_in[11];
    const float* b_fc1  = (const float*)d_in[12];
    const float* w_fc2  = (const float*)d_in[13];
    const float* b_fc2  = (const float*)d_in[14];
    float* out = (float*)d_out;                      // f32 output

    // ws: converted bf16 weights only — 786432 elems = 1.5 MiB
    unsigned short* cWqkv  = (unsigned short*)d_ws;  // 196608
    unsigned short* cWproj = cWqkv  + 196608;        // 65536
    unsigned short* cWfc1  = cWproj + 65536;         // 262144
    unsigned short* cWfc2  = cWfc1  + 262144;        // 262144

    conv_k<<<192, 256, 0, stream>>>(w_qkv,  cWqkv,  49152);
    conv_k<<<64,  256, 0, stream>>>(w_proj, cWproj, 16384);
    conv_k<<<256, 256, 0, stream>>>(w_fc1,  cWfc1,  65536);
    conv_k<<<256, 256, 0, stream>>>(w_fc2,  cWfc2,  65536);

    attn_half_k<<<2048, 1024, 0, stream>>>(x, g1, b1, cWqkv, b_qkv, cWproj, b_proj, out);
    mlp_half_k<<<1568, 512, 0, stream>>>(g2, b2, cWfc1, b_fc1, cWfc2, b_fc2, out);
}